// Round 14
// baseline (322.703 us; speedup 1.0000x reference)
//
#include <hip/hip_runtime.h>

#define N_NODES   50000
#define M_PAD     50048            // 1564 * 32
#define N_TILES   1564
#define GEMM_GRID 782              // 2 tiles per block
#define N_EDGES   800000
#define HID       128
#define OUT_DIM   64
#define NUM_GRAPHS 512
#define EPS       1e-6f
#define NBUCK     196
#define BUCKCAP   6144
#define ABLOCKS   98
#define SS        (M_PAD * 16)     // slice stride (elements)

typedef __attribute__((ext_vector_type(8))) short short8;
typedef __attribute__((ext_vector_type(16))) float f32x16;

static __device__ __forceinline__ unsigned short f2bf(float f) {
    unsigned u = __builtin_bit_cast(unsigned, f);
    u += 0x7FFFu + ((u >> 16) & 1u);           // round-to-nearest-even
    return (unsigned short)(u >> 16);
}
static __device__ __forceinline__ float bf2f(unsigned short h) {
    unsigned u = ((unsigned)h) << 16;
    return __builtin_bit_cast(float, u);
}

static __device__ __forceinline__ float signpow(float x, bool sqrt_mode) {
    if (x == 0.0f) return 0.0f;
    float a = fabsf(x) + EPS;
    float v = sqrt_mode ? sqrtf(a) : a * a;
    return x > 0.0f ? v : -v;
}

// ---- CSR build, pass A: bucket edges by dst>>8 -----------------------------
__global__ __launch_bounds__(256) void k_bucketize(const int* __restrict__ ei,
                                                   int* __restrict__ gcnt,
                                                   unsigned* __restrict__ ebuf) {
    __shared__ int lcnt[NBUCK];
    __shared__ int lbase[NBUCK];
    int tid = threadIdx.x;
    for (int i = tid; i < NBUCK; i += 256) lcnt[i] = 0;
    __syncthreads();

    const uint4* src4 = (const uint4*)ei;
    const uint4* dst4 = (const uint4*)(ei + N_EDGES);
    int base4 = blockIdx.x * 2048;

    #pragma unroll 1
    for (int it = 0; it < 8; it++) {
        int i4 = base4 + it * 256 + tid;
        if (i4 < N_EDGES / 4) {
            uint4 d = dst4[i4];
            atomicAdd(&lcnt[d.x >> 8], 1);
            atomicAdd(&lcnt[d.y >> 8], 1);
            atomicAdd(&lcnt[d.z >> 8], 1);
            atomicAdd(&lcnt[d.w >> 8], 1);
        }
    }
    __syncthreads();
    for (int i = tid; i < NBUCK; i += 256) {
        lbase[i] = atomicAdd(&gcnt[i], lcnt[i]);
        lcnt[i] = 0;
    }
    __syncthreads();

    #pragma unroll 1
    for (int it = 0; it < 8; it++) {
        int i4 = base4 + it * 256 + tid;
        if (i4 < N_EDGES / 4) {
            uint4 d = dst4[i4];
            uint4 s = src4[i4];
            unsigned dd[4] = {d.x, d.y, d.z, d.w};
            unsigned ss[4] = {s.x, s.y, s.z, s.w};
            #pragma unroll
            for (int k = 0; k < 4; k++) {
                int b = dd[k] >> 8;
                int p = atomicAdd(&lcnt[b], 1);
                ebuf[(size_t)b * BUCKCAP + lbase[b] + p] = ss[k] | (dd[k] << 16);
            }
        }
    }
}

// ---- pass B: bucket prefix (internal) + per-node count/scan/fill ----------
__global__ __launch_bounds__(256) void k_csr(const unsigned* __restrict__ ebuf,
                                             const int* __restrict__ gcnt,
                                             int* __restrict__ offs,
                                             float* __restrict__ dis,
                                             int* __restrict__ csr) {
    __shared__ int cntA[256];
    __shared__ int scanA[256];
    __shared__ int sbase;
    int b = blockIdx.x;
    int t = threadIdx.x;
    int n0 = b * 256;

    int v = (t < NBUCK) ? gcnt[t] : 0;
    scanA[t] = v;
    __syncthreads();
    for (int off = 1; off < 256; off <<= 1) {
        int u = (t >= off) ? scanA[t - off] : 0;
        __syncthreads();
        scanA[t] += u;
        __syncthreads();
    }
    if (t == 0) sbase = (b == 0) ? 0 : scanA[b - 1];
    __syncthreads();
    int base  = sbase;
    int count = gcnt[b];
    const unsigned* eb = ebuf + (size_t)b * BUCKCAP;

    cntA[t] = 0;
    __syncthreads();
    for (int i = t; i < count; i += 256)
        atomicAdd(&cntA[eb[i] >> 16 & 0xFF], 1);
    __syncthreads();
    int c = cntA[t];
    scanA[t] = c;
    __syncthreads();
    for (int off = 1; off < 256; off <<= 1) {
        int u = (t >= off) ? scanA[t - off] : 0;
        __syncthreads();
        scanA[t] += u;
        __syncthreads();
    }
    int excl = scanA[t] - c;
    int n = n0 + t;
    if (n < N_NODES) {
        offs[n] = base + excl;
        dis[n]  = rsqrtf((float)c + 1.0f);
    }
    if (b == 0 && t == 0) offs[N_NODES] = N_EDGES;
    scanA[t] = excl;
    cntA[t] = 0;
    __syncthreads();
    for (int i = t; i < count; i += 256) {
        unsigned vv = eb[i];
        int ln = (vv >> 16) & 0xFF;
        int p = atomicAdd(&cntA[ln], 1);
        csr[base + scanA[ln] + p] = (int)(vv & 0xFFFFu);
    }
}

// ---- all three W[128k x 128n] -> W^T splits [3][128n][128k] hi/lo ----------
__global__ void k_wsplit3(const float* __restrict__ W0, const float* __restrict__ W1,
                          const float* __restrict__ W2, short* __restrict__ Wth,
                          short* __restrict__ Wtl) {
    int which = blockIdx.y;
    const float* W = which == 0 ? W0 : (which == 1 ? W1 : W2);
    int tid = blockIdx.x * blockDim.x + threadIdx.x;   // 16384
    int k = tid & 127, n = tid >> 7;
    float w = W[k * HID + n];
    unsigned short h = f2bf(w);
    Wth[which * HID * HID + n * HID + k] = (short)h;
    Wtl[which * HID * HID + n * HID + k] = (short)f2bf(w - bf2f(h));
}

// ---- MFMA GEMM (32x32x16): W in regs, A staged via LDS --------------------
// Output th is SLICE-BLOCKED bf16 [8][M_PAD][16].
// FP32SRC=1: A = fp32 row-major [N_NODES x 128] (hi/lo split in staging).
// FP32SRC=0: A = slice-blocked bf16 hi/lo pair [8][M_PAD][16] each.
template<int FP32SRC>
__global__ __launch_bounds__(256) void k_gemm_mfma(const void* __restrict__ Asrc_h,
                                                   const void* __restrict__ Asrc_l,
                                                   const short* __restrict__ Wh,
                                                   const short* __restrict__ Wl,
                                                   unsigned short* __restrict__ th,
                                                   const float* __restrict__ scale) {
    __shared__ short As_h[32 * 128];   // 8 KB, col-group XOR-swizzled by row&7
    __shared__ short As_l[32 * 128];   // 8 KB
    int tid  = threadIdx.x;
    int lane = tid & 63;
    int col  = (tid >> 6) * 32 + (lane & 31);
    int kh   = lane >> 5;
    int r    = lane & 31;

    short8 bh[8], bl[8];
    #pragma unroll
    for (int ks = 0; ks < 8; ks++) {
        bh[ks] = *(const short8*)(Wh + (size_t)col * HID + ks * 16 + kh * 8);
        bl[ks] = *(const short8*)(Wl + (size_t)col * HID + ks * 16 + kh * 8);
    }

    // row-major staging indices (FP32SRC=1): unit u = (row u>>4, colgroup u&15)
    int su0 = tid, su1 = tid + 256;
    int sr0 = su0 >> 4, sc0 = su0 & 15;
    int sr1 = su1 >> 4, sc1 = su1 & 15;
    int sw0 = sr0 * 128 + ((sc0 ^ (sr0 & 7)) * 8);
    int sw1 = sr1 * 128 + ((sc1 ^ (sr1 & 7)) * 8);

    int oslice = col >> 4, oc16 = col & 15;
    unsigned short* thp = th + (size_t)oslice * SS;

    for (int tile = blockIdx.x; tile < N_TILES; tile += GEMM_GRID) {
        int row0 = tile * 32;
        __syncthreads();
        if (FP32SRC) {
            const float* gx = (const float*)Asrc_h;
            #pragma unroll
            for (int u = 0; u < 2; u++) {
                int sr = u ? sr1 : sr0, sc = u ? sc1 : sc0, sw = u ? sw1 : sw0;
                int gr = row0 + sr; if (gr >= N_NODES) gr = N_NODES - 1;
                const float* src = gx + (size_t)gr * HID + sc * 8;
                float4 a = ((const float4*)src)[0];
                float4 b = ((const float4*)src)[1];
                float vals[8] = {a.x, a.y, a.z, a.w, b.x, b.y, b.z, b.w};
                short8 hi, lo;
                #pragma unroll
                for (int j = 0; j < 8; j++) {
                    unsigned short hh = f2bf(vals[j]);
                    hi[j] = (short)hh;
                    lo[j] = (short)f2bf(vals[j] - bf2f(hh));
                }
                *(short8*)&As_h[sw] = hi;
                *(short8*)&As_l[sw] = lo;
            }
        } else {
            // slice-blocked source: unit u -> s=u>>6, r=(u>>1)&31, half=u&1
            const short* gh = (const short*)Asrc_h;
            const short* gl = (const short*)Asrc_l;
            #pragma unroll
            for (int u = 0; u < 2; u++) {
                int uu = u ? (tid + 256) : tid;
                int s = uu >> 6, rr = (uu >> 1) & 31, half = uu & 1;
                int cg = s * 2 + half;
                int sw = rr * 128 + ((cg ^ (rr & 7)) * 8);
                size_t off = (size_t)s * SS + (size_t)(row0 + rr) * 16 + half * 8;
                *(short8*)&As_h[sw] = *(const short8*)(gh + off);
                *(short8*)&As_l[sw] = *(const short8*)(gl + off);
            }
        }
        __syncthreads();

        short8 ah[8], al[8];
        #pragma unroll
        for (int ks = 0; ks < 8; ks++) {
            int cg = ks * 2 + kh;
            int off = r * 128 + ((cg ^ (r & 7)) * 8);
            ah[ks] = *(const short8*)&As_h[off];
            al[ks] = *(const short8*)&As_l[off];
        }

        f32x16 acc = {0.f};
        #pragma unroll
        for (int ks = 0; ks < 8; ks++) {
            acc = __builtin_amdgcn_mfma_f32_32x32x16_bf16(ah[ks], bh[ks], acc, 0, 0, 0);
            acc = __builtin_amdgcn_mfma_f32_32x32x16_bf16(al[ks], bh[ks], acc, 0, 0, 0);
            acc = __builtin_amdgcn_mfma_f32_32x32x16_bf16(ah[ks], bl[ks], acc, 0, 0, 0);
        }

        #pragma unroll
        for (int reg = 0; reg < 16; reg++) {
            int row = row0 + (reg & 3) + 8 * (reg >> 2) + 4 * kh;
            float v = acc[reg] * scale[row];
            thp[(size_t)row * 16 + oc16] = f2bf(v);
        }
    }
}

// ---- GCN aggregation, slice-partitioned (slice = bid&7 -> XCD-local L2) ----
// th slice-blocked bf16. Per block: 8 nodes x 16 cols. 32 lanes/node:
// cg = lane&3 (ushort4 = 4 cols), e = (lane>>2)&7 (8 edge slots).
__global__ __launch_bounds__(256) void k_agg(const unsigned short* __restrict__ th,
                                             const int* __restrict__ offs,
                                             const int* __restrict__ csr_src,
                                             const float* __restrict__ dis,
                                             const float* __restrict__ bias,
                                             float* __restrict__ hout,
                                             short* __restrict__ hh,
                                             short* __restrict__ hl,
                                             int mode) {
    int slice = blockIdx.x & 7;
    int ng    = blockIdx.x >> 3;
    int tid   = threadIdx.x;
    int wave  = tid >> 6, lane = tid & 63;
    int nhalf = lane >> 5;
    int l32   = lane & 31;
    int cg    = l32 & 3;
    int e     = l32 >> 2;
    int node  = ng * 8 + wave * 2 + nhalf;
    if (node >= N_NODES) return;

    int beg = offs[node], end = offs[node + 1];
    float dn = dis[node];
    const unsigned short* tb = th + (size_t)slice * SS;

    float a0 = 0.f, a1 = 0.f, a2 = 0.f, a3 = 0.f;
    for (int j = beg; j < end; j += 8) {
        int jj = j + e;
        int jc = jj < end ? jj : end - 1;
        int s = csr_src[jc];
        float m = (jj < end) ? 1.0f : 0.0f;
        ushort4 v = *(const ushort4*)&tb[(size_t)s * 16 + cg * 4];
        a0 = fmaf(bf2f(v.x), m, a0);
        a1 = fmaf(bf2f(v.y), m, a1);
        a2 = fmaf(bf2f(v.z), m, a2);
        a3 = fmaf(bf2f(v.w), m, a3);
    }
    // reduce over 8 edge slots (lane bits 2..4)
    #pragma unroll
    for (int msk = 4; msk <= 16; msk <<= 1) {
        a0 += __shfl_xor(a0, msk);
        a1 += __shfl_xor(a1, msk);
        a2 += __shfl_xor(a2, msk);
        a3 += __shfl_xor(a3, msk);
    }

    if (e == 0) {
        ushort4 sh = *(const ushort4*)&tb[(size_t)node * 16 + cg * 4];
        float4 b4  = *(const float4*)&bias[slice * 16 + cg * 4];
        float o0 = (a0 + bf2f(sh.x)) * dn + b4.x;
        float o1 = (a1 + bf2f(sh.y)) * dn + b4.y;
        float o2 = (a2 + bf2f(sh.z)) * dn + b4.z;
        float o3 = (a3 + bf2f(sh.w)) * dn + b4.w;
        size_t ob = (size_t)slice * SS + (size_t)node * 16 + cg * 4;
        if (mode == 1) {
            o0 = fmaxf(o0, 0.f); o1 = fmaxf(o1, 0.f);
            o2 = fmaxf(o2, 0.f); o3 = fmaxf(o3, 0.f);
            unsigned short h0 = f2bf(o0), h1 = f2bf(o1), h2 = f2bf(o2), h3 = f2bf(o3);
            ushort4 vh; vh.x = h0; vh.y = h1; vh.z = h2; vh.w = h3;
            ushort4 vl;
            vl.x = f2bf(o0 - bf2f(h0)); vl.y = f2bf(o1 - bf2f(h1));
            vl.z = f2bf(o2 - bf2f(h2)); vl.w = f2bf(o3 - bf2f(h3));
            *(ushort4*)&hh[ob] = vh;
            *(ushort4*)&hl[ob] = vl;
        } else {
            float4 o = make_float4(o0, o1, o2, o3);
            *(float4*)&hout[ob] = o;
        }
    }
}

// ---- pool (gen-mean p=2) + FF head; h is slice-blocked fp32 [8][M_PAD][16] -
__global__ __launch_bounds__(256) void k_poolff(const float* __restrict__ h,
                                                const int* __restrict__ batch,
                                                const float* __restrict__ Wf0,
                                                const float* __restrict__ bf0,
                                                const float* __restrict__ Wf1,
                                                const float* __restrict__ bf1,
                                                float* __restrict__ out) {
    __shared__ float smx[4][64], smy[4][64];
    __shared__ float row[128], zrow[128];
    __shared__ int bnd[2];
    int g = blockIdx.x;
    int t = threadIdx.x;
    if (t < 2) {
        int target = g + t;
        int lo = 0, hi = N_NODES;
        while (lo < hi) {
            int mid = (lo + hi) >> 1;
            if (batch[mid] < target) lo = mid + 1; else hi = mid;
        }
        bnd[t] = lo;
    }
    __syncthreads();
    int beg = bnd[0], end = bnd[1];

    int c = t & 63, slot = t >> 6;
    size_t sbase = (size_t)(c >> 3) * SS + (size_t)(c & 7) * 2;
    float sx = 0.f, sy = 0.f;
    for (int n = beg + slot; n < end; n += 4) {
        float2 v = *(const float2*)&h[sbase + (size_t)n * 16];
        sx += signpow(v.x, false);
        sy += signpow(v.y, false);
    }
    smx[slot][c] = sx; smy[slot][c] = sy;
    __syncthreads();
    if (slot == 0) {
        sx = (smx[0][c] + smx[1][c]) + (smx[2][c] + smx[3][c]);
        sy = (smy[0][c] + smy[1][c]) + (smy[2][c] + smy[3][c]);
        float cnt = fmaxf((float)(end - beg), 1.0f);
        row[c * 2]     = fmaxf(signpow(sx / cnt, true), 0.f);
        row[c * 2 + 1] = fmaxf(signpow(sy / cnt, true), 0.f);
    }
    __syncthreads();
    if (t < 128) {
        float acc = bf0[t];
        #pragma unroll 8
        for (int k = 0; k < 128; k++) acc = fmaf(row[k], Wf0[k * 128 + t], acc);
        zrow[t] = fmaxf(acc, 0.f);
    }
    __syncthreads();
    if (t < OUT_DIM) {
        float a2 = bf1[t];
        #pragma unroll 8
        for (int k = 0; k < 128; k++) a2 = fmaf(zrow[k], Wf1[k * OUT_DIM + t], a2);
        out[g * OUT_DIM + t] = a2;
    }
}

// ---------------------------------------------------------------------------
static inline size_t align256(size_t x) { return (x + 255) & ~(size_t)255; }

extern "C" void kernel_launch(void* const* d_in, const int* in_sizes, int n_in,
                              void* d_out, int out_size, void* d_ws, size_t ws_size,
                              hipStream_t stream) {
    const float* x     = (const float*)d_in[0];
    const int*   ei    = (const int*)d_in[1];
    const int*   batch = (const int*)d_in[2];
    const float* W0  = (const float*)d_in[3];  const float* b0  = (const float*)d_in[4];
    const float* W1  = (const float*)d_in[5];  const float* b1  = (const float*)d_in[6];
    const float* W2  = (const float*)d_in[7];  const float* b2  = (const float*)d_in[8];
    const float* Wf0 = (const float*)d_in[9];  const float* bf0 = (const float*)d_in[10];
    const float* Wf1 = (const float*)d_in[11]; const float* bf1 = (const float*)d_in[12];
    float* out = (float*)d_out;

    char* p = (char*)d_ws;
    unsigned short* th = (unsigned short*)p; p += align256((size_t)M_PAD * HID * 2);
    short* bufAh = (short*)p; p += align256((size_t)M_PAD * HID * 2);
    short* bufAl = (short*)p; p += align256((size_t)M_PAD * HID * 2);
    short* bufBh = (short*)p; p += align256((size_t)M_PAD * HID * 2);
    short* bufBl = (short*)p; p += align256((size_t)M_PAD * HID * 2);
    float* h     = (float*)bufBh;   // aliases bufBh+bufBl (25.6 MB), live only after layer2
    unsigned* ebuf = (unsigned*)p; p += align256((size_t)NBUCK * BUCKCAP * 4);
    int*   gcnt    = (int*)p;   p += align256((size_t)NBUCK * 4);
    int*   offs    = (int*)p;   p += align256((size_t)(N_NODES + 1) * 4);
    int*   csr     = (int*)p;   p += align256((size_t)N_EDGES * 4);
    float* dis     = (float*)p; p += align256((size_t)N_NODES * 4);
    short* Wth     = (short*)p; p += align256((size_t)3 * HID * HID * 2);
    short* Wtl     = (short*)p; p += align256((size_t)3 * HID * HID * 2);

    hipMemsetAsync(gcnt, 0, (size_t)NBUCK * 4, stream);

    k_bucketize<<<ABLOCKS, 256, 0, stream>>>(ei, gcnt, ebuf);
    k_csr      <<<NBUCK, 256, 0, stream>>>(ebuf, gcnt, offs, dis, csr);

    dim3 wg(64, 3);
    k_wsplit3<<<wg, 256, 0, stream>>>(W0, W1, W2, Wth, Wtl);

    int agg_blocks = (N_NODES / 8) * 8;   // 50000 blocks: 6250 node-groups x 8 slices

    // layer 0: GEMM reads fp32 x directly
    k_gemm_mfma<1><<<GEMM_GRID, 256, 0, stream>>>(x, nullptr, Wth, Wtl, th, dis);
    k_agg<<<agg_blocks, 256, 0, stream>>>(th, offs, csr, dis, b0,
                                          nullptr, bufBh, bufBl, 1);
    // layer 1
    k_gemm_mfma<0><<<GEMM_GRID, 256, 0, stream>>>(bufBh, bufBl,
                                                  Wth + HID * HID, Wtl + HID * HID, th, dis);
    k_agg<<<agg_blocks, 256, 0, stream>>>(th, offs, csr, dis, b1,
                                          nullptr, bufAh, bufAl, 1);
    // layer 2 (no relu, fp32 slice-blocked out for pooling)
    k_gemm_mfma<0><<<GEMM_GRID, 256, 0, stream>>>(bufAh, bufAl,
                                                  Wth + 2 * HID * HID, Wtl + 2 * HID * HID, th, dis);
    k_agg<<<agg_blocks, 256, 0, stream>>>(th, offs, csr, dis, b2,
                                          h, nullptr, nullptr, 0);

    k_poolff<<<NUM_GRAPHS, 256, 0, stream>>>(h, batch, Wf0, bf0, Wf1, bf1, out);
}

// Round 15
// 206.803 us; speedup vs baseline: 1.5604x; 1.5604x over previous
//
#include <hip/hip_runtime.h>

#define N_NODES   50000
#define M_PAD     50048            // 1564 * 32
#define N_TILES   1564
#define GEMM_GRID 782              // 2 tiles per block
#define N_EDGES   800000
#define HID       128
#define OUT_DIM   64
#define NUM_GRAPHS 512
#define EPS       1e-6f
#define NBUCK     196
#define BUCKCAP   6144
#define ABLOCKS   98

typedef __attribute__((ext_vector_type(8))) short short8;
typedef __attribute__((ext_vector_type(16))) float f32x16;

static __device__ __forceinline__ unsigned short f2bf(float f) {
    unsigned u = __builtin_bit_cast(unsigned, f);
    u += 0x7FFFu + ((u >> 16) & 1u);           // round-to-nearest-even
    return (unsigned short)(u >> 16);
}
static __device__ __forceinline__ float bf2f(unsigned short h) {
    unsigned u = ((unsigned)h) << 16;
    return __builtin_bit_cast(float, u);
}
static __device__ __forceinline__ float lo16(unsigned w) {
    return __builtin_bit_cast(float, w << 16);
}
static __device__ __forceinline__ float hi16(unsigned w) {
    return __builtin_bit_cast(float, w & 0xFFFF0000u);
}

static __device__ __forceinline__ float signpow(float x, bool sqrt_mode) {
    if (x == 0.0f) return 0.0f;
    float a = fabsf(x) + EPS;
    float v = sqrt_mode ? sqrtf(a) : a * a;
    return x > 0.0f ? v : -v;
}

// ---- CSR build, pass A: bucket edges by dst>>8 -----------------------------
__global__ __launch_bounds__(256) void k_bucketize(const int* __restrict__ ei,
                                                   int* __restrict__ gcnt,
                                                   unsigned* __restrict__ ebuf) {
    __shared__ int lcnt[NBUCK];
    __shared__ int lbase[NBUCK];
    int tid = threadIdx.x;
    for (int i = tid; i < NBUCK; i += 256) lcnt[i] = 0;
    __syncthreads();

    const uint4* src4 = (const uint4*)ei;
    const uint4* dst4 = (const uint4*)(ei + N_EDGES);
    int base4 = blockIdx.x * 2048;

    #pragma unroll 1
    for (int it = 0; it < 8; it++) {
        int i4 = base4 + it * 256 + tid;
        if (i4 < N_EDGES / 4) {
            uint4 d = dst4[i4];
            atomicAdd(&lcnt[d.x >> 8], 1);
            atomicAdd(&lcnt[d.y >> 8], 1);
            atomicAdd(&lcnt[d.z >> 8], 1);
            atomicAdd(&lcnt[d.w >> 8], 1);
        }
    }
    __syncthreads();
    for (int i = tid; i < NBUCK; i += 256) {
        lbase[i] = atomicAdd(&gcnt[i], lcnt[i]);
        lcnt[i] = 0;
    }
    __syncthreads();

    #pragma unroll 1
    for (int it = 0; it < 8; it++) {
        int i4 = base4 + it * 256 + tid;
        if (i4 < N_EDGES / 4) {
            uint4 d = dst4[i4];
            uint4 s = src4[i4];
            unsigned dd[4] = {d.x, d.y, d.z, d.w};
            unsigned ss[4] = {s.x, s.y, s.z, s.w};
            #pragma unroll
            for (int k = 0; k < 4; k++) {
                int b = dd[k] >> 8;
                int p = atomicAdd(&lcnt[b], 1);
                ebuf[(size_t)b * BUCKCAP + lbase[b] + p] = ss[k] | (dd[k] << 16);
            }
        }
    }
}

// ---- pass B: bucket prefix (internal) + per-node count/scan/fill ----------
__global__ __launch_bounds__(256) void k_csr(const unsigned* __restrict__ ebuf,
                                             const int* __restrict__ gcnt,
                                             int* __restrict__ offs,
                                             float* __restrict__ dis,
                                             int* __restrict__ csr) {
    __shared__ int cntA[256];
    __shared__ int scanA[256];
    __shared__ int sbase;
    int b = blockIdx.x;
    int t = threadIdx.x;
    int n0 = b * 256;

    int v = (t < NBUCK) ? gcnt[t] : 0;
    scanA[t] = v;
    __syncthreads();
    for (int off = 1; off < 256; off <<= 1) {
        int u = (t >= off) ? scanA[t - off] : 0;
        __syncthreads();
        scanA[t] += u;
        __syncthreads();
    }
    if (t == 0) sbase = (b == 0) ? 0 : scanA[b - 1];
    __syncthreads();
    int base  = sbase;
    int count = gcnt[b];
    const unsigned* eb = ebuf + (size_t)b * BUCKCAP;

    cntA[t] = 0;
    __syncthreads();
    for (int i = t; i < count; i += 256)
        atomicAdd(&cntA[eb[i] >> 16 & 0xFF], 1);
    __syncthreads();
    int c = cntA[t];
    scanA[t] = c;
    __syncthreads();
    for (int off = 1; off < 256; off <<= 1) {
        int u = (t >= off) ? scanA[t - off] : 0;
        __syncthreads();
        scanA[t] += u;
        __syncthreads();
    }
    int excl = scanA[t] - c;
    int n = n0 + t;
    if (n < N_NODES) {
        offs[n] = base + excl;
        dis[n]  = rsqrtf((float)c + 1.0f);
    }
    if (b == 0 && t == 0) offs[N_NODES] = N_EDGES;
    scanA[t] = excl;
    cntA[t] = 0;
    __syncthreads();
    for (int i = t; i < count; i += 256) {
        unsigned vv = eb[i];
        int ln = (vv >> 16) & 0xFF;
        int p = atomicAdd(&cntA[ln], 1);
        csr[base + scanA[ln] + p] = (int)(vv & 0xFFFFu);
    }
}

// ---- all three W[128k x 128n] -> W^T splits [3][128n][128k] hi/lo ----------
__global__ void k_wsplit3(const float* __restrict__ W0, const float* __restrict__ W1,
                          const float* __restrict__ W2, short* __restrict__ Wth,
                          short* __restrict__ Wtl) {
    int which = blockIdx.y;
    const float* W = which == 0 ? W0 : (which == 1 ? W1 : W2);
    int tid = blockIdx.x * blockDim.x + threadIdx.x;   // 16384
    int k = tid & 127, n = tid >> 7;
    float w = W[k * HID + n];
    unsigned short h = f2bf(w);
    Wth[which * HID * HID + n * HID + k] = (short)h;
    Wtl[which * HID * HID + n * HID + k] = (short)f2bf(w - bf2f(h));
}

// ---- MFMA GEMM (32x32x16): W in regs, A staged via LDS; th (bf16) out ------
// FP32SRC=1: A is fp32 [N_NODES x 128], hi/lo split computed during staging.
// FP32SRC=0: A given as bf16 hi/lo pair [M_PAD x 128] row-major.
template<int FP32SRC>
__global__ __launch_bounds__(256) void k_gemm_mfma(const void* __restrict__ Asrc_h,
                                                   const void* __restrict__ Asrc_l,
                                                   const short* __restrict__ Wh,
                                                   const short* __restrict__ Wl,
                                                   unsigned short* __restrict__ th,
                                                   const float* __restrict__ scale) {
    __shared__ short As_h[32 * 128];   // 8 KB, col-group XOR-swizzled by row&7
    __shared__ short As_l[32 * 128];   // 8 KB
    int tid  = threadIdx.x;
    int lane = tid & 63;
    int col  = (tid >> 6) * 32 + (lane & 31);
    int kh   = lane >> 5;
    int r    = lane & 31;

    short8 bh[8], bl[8];
    #pragma unroll
    for (int ks = 0; ks < 8; ks++) {
        bh[ks] = *(const short8*)(Wh + (size_t)col * HID + ks * 16 + kh * 8);
        bl[ks] = *(const short8*)(Wl + (size_t)col * HID + ks * 16 + kh * 8);
    }

    int su0 = tid, su1 = tid + 256;
    int sr0 = su0 >> 4, sc0 = su0 & 15;
    int sr1 = su1 >> 4, sc1 = su1 & 15;
    int sw0 = sr0 * 128 + ((sc0 ^ (sr0 & 7)) * 8);
    int sw1 = sr1 * 128 + ((sc1 ^ (sr1 & 7)) * 8);

    for (int tile = blockIdx.x; tile < N_TILES; tile += GEMM_GRID) {
        int row0 = tile * 32;
        __syncthreads();
        if (FP32SRC) {
            const float* gx = (const float*)Asrc_h;
            #pragma unroll
            for (int u = 0; u < 2; u++) {
                int sr = u ? sr1 : sr0, sc = u ? sc1 : sc0, sw = u ? sw1 : sw0;
                int gr = row0 + sr; if (gr >= N_NODES) gr = N_NODES - 1;
                const float* src = gx + (size_t)gr * HID + sc * 8;
                float4 a = ((const float4*)src)[0];
                float4 b = ((const float4*)src)[1];
                float vals[8] = {a.x, a.y, a.z, a.w, b.x, b.y, b.z, b.w};
                short8 hi, lo;
                #pragma unroll
                for (int j = 0; j < 8; j++) {
                    unsigned short hh = f2bf(vals[j]);
                    hi[j] = (short)hh;
                    lo[j] = (short)f2bf(vals[j] - bf2f(hh));
                }
                *(short8*)&As_h[sw] = hi;
                *(short8*)&As_l[sw] = lo;
            }
        } else {
            const short* gh = (const short*)Asrc_h + (size_t)row0 * HID;
            const short* gl = (const short*)Asrc_l + (size_t)row0 * HID;
            *(short8*)&As_h[sw0] = *(const short8*)(gh + sr0 * HID + sc0 * 8);
            *(short8*)&As_h[sw1] = *(const short8*)(gh + sr1 * HID + sc1 * 8);
            *(short8*)&As_l[sw0] = *(const short8*)(gl + sr0 * HID + sc0 * 8);
            *(short8*)&As_l[sw1] = *(const short8*)(gl + sr1 * HID + sc1 * 8);
        }
        __syncthreads();

        short8 ah[8], al[8];
        #pragma unroll
        for (int ks = 0; ks < 8; ks++) {
            int cg = ks * 2 + kh;
            int off = r * 128 + ((cg ^ (r & 7)) * 8);
            ah[ks] = *(const short8*)&As_h[off];
            al[ks] = *(const short8*)&As_l[off];
        }

        f32x16 acc = {0.f};
        #pragma unroll
        for (int ks = 0; ks < 8; ks++) {
            acc = __builtin_amdgcn_mfma_f32_32x32x16_bf16(ah[ks], bh[ks], acc, 0, 0, 0);
            acc = __builtin_amdgcn_mfma_f32_32x32x16_bf16(al[ks], bh[ks], acc, 0, 0, 0);
            acc = __builtin_amdgcn_mfma_f32_32x32x16_bf16(ah[ks], bl[ks], acc, 0, 0, 0);
        }

        #pragma unroll
        for (int reg = 0; reg < 16; reg++) {
            int row = row0 + (reg & 3) + 8 * (reg >> 2) + 4 * kh;
            float v = acc[reg] * scale[row];
            th[(size_t)row * HID + col] = f2bf(v);
        }
    }
}

// ---- GCN aggregation: row-major gather, uint4 (8 cols) per lane ------------
// 64 lanes/node: c = lane&15 (8-col groups), e = lane>>4 (4 edge slots).
__global__ __launch_bounds__(256) void k_agg(const unsigned short* __restrict__ th,
                                             const int* __restrict__ offs,
                                             const int* __restrict__ csr_src,
                                             const float* __restrict__ dis,
                                             const float* __restrict__ bias,
                                             float* __restrict__ hout,
                                             short* __restrict__ hh,
                                             short* __restrict__ hl,
                                             int mode) {
    int node = blockIdx.x * 4 + (threadIdx.x >> 6);
    if (node >= N_NODES) return;
    int lane = threadIdx.x & 63;
    int c  = lane & 15;          // col group: cols [c*8, c*8+8)
    int e  = lane >> 4;          // edge slot 0..3
    int beg = offs[node], end = offs[node + 1];
    float dn = dis[node];

    float a[8] = {};
    for (int j = beg; j < end; j += 8) {
        #pragma unroll
        for (int k = 0; k < 2; k++) {
            int jj = j + k * 4 + e;
            int jc = jj < end ? jj : end - 1;
            int s = csr_src[jc];
            float m = (jj < end) ? 1.0f : 0.0f;
            uint4 v = *(const uint4*)&th[(size_t)s * HID + c * 8];
            a[0] = fmaf(lo16(v.x), m, a[0]);
            a[1] = fmaf(hi16(v.x), m, a[1]);
            a[2] = fmaf(lo16(v.y), m, a[2]);
            a[3] = fmaf(hi16(v.y), m, a[3]);
            a[4] = fmaf(lo16(v.z), m, a[4]);
            a[5] = fmaf(hi16(v.z), m, a[5]);
            a[6] = fmaf(lo16(v.w), m, a[6]);
            a[7] = fmaf(hi16(v.w), m, a[7]);
        }
    }
    // reduce over the 4 edge slots (lane bits 4,5)
    #pragma unroll
    for (int i = 0; i < 8; i++) {
        a[i] += __shfl_xor(a[i], 16);
        a[i] += __shfl_xor(a[i], 32);
    }

    if (e == 0) {
        uint4 sh = *(const uint4*)&th[(size_t)node * HID + c * 8];
        float4 b0 = *(const float4*)&bias[c * 8];
        float4 b1 = *(const float4*)&bias[c * 8 + 4];
        float o[8];
        o[0] = (a[0] + lo16(sh.x)) * dn + b0.x;
        o[1] = (a[1] + hi16(sh.x)) * dn + b0.y;
        o[2] = (a[2] + lo16(sh.y)) * dn + b0.z;
        o[3] = (a[3] + hi16(sh.y)) * dn + b0.w;
        o[4] = (a[4] + lo16(sh.z)) * dn + b1.x;
        o[5] = (a[5] + hi16(sh.z)) * dn + b1.y;
        o[6] = (a[6] + lo16(sh.w)) * dn + b1.z;
        o[7] = (a[7] + hi16(sh.w)) * dn + b1.w;
        if (mode == 1) {
            ushort4 vh0, vh1, vl0, vl1;
            unsigned short hb[8], lb[8];
            #pragma unroll
            for (int i = 0; i < 8; i++) {
                o[i] = fmaxf(o[i], 0.f);
                hb[i] = f2bf(o[i]);
                lb[i] = f2bf(o[i] - bf2f(hb[i]));
            }
            vh0.x = hb[0]; vh0.y = hb[1]; vh0.z = hb[2]; vh0.w = hb[3];
            vh1.x = hb[4]; vh1.y = hb[5]; vh1.z = hb[6]; vh1.w = hb[7];
            vl0.x = lb[0]; vl0.y = lb[1]; vl0.z = lb[2]; vl0.w = lb[3];
            vl1.x = lb[4]; vl1.y = lb[5]; vl1.z = lb[6]; vl1.w = lb[7];
            *(ushort4*)&hh[(size_t)node * HID + c * 8]     = vh0;
            *(ushort4*)&hh[(size_t)node * HID + c * 8 + 4] = vh1;
            *(ushort4*)&hl[(size_t)node * HID + c * 8]     = vl0;
            *(ushort4*)&hl[(size_t)node * HID + c * 8 + 4] = vl1;
        } else {
            float4 o0 = make_float4(o[0], o[1], o[2], o[3]);
            float4 o1 = make_float4(o[4], o[5], o[6], o[7]);
            *(float4*)&hout[(size_t)node * HID + c * 8]     = o0;
            *(float4*)&hout[(size_t)node * HID + c * 8 + 4] = o1;
        }
    }
}

// ---- pool (gen-mean p=2) + FF head, one block per graph --------------------
__global__ __launch_bounds__(256) void k_poolff(const float* __restrict__ h,
                                                const int* __restrict__ batch,
                                                const float* __restrict__ Wf0,
                                                const float* __restrict__ bf0,
                                                const float* __restrict__ Wf1,
                                                const float* __restrict__ bf1,
                                                float* __restrict__ out) {
    __shared__ float smx[4][64], smy[4][64];
    __shared__ float row[128], zrow[128];
    __shared__ int bnd[2];
    int g = blockIdx.x;
    int t = threadIdx.x;
    if (t < 2) {
        int target = g + t;
        int lo = 0, hi = N_NODES;
        while (lo < hi) {
            int mid = (lo + hi) >> 1;
            if (batch[mid] < target) lo = mid + 1; else hi = mid;
        }
        bnd[t] = lo;
    }
    __syncthreads();
    int beg = bnd[0], end = bnd[1];

    int c = t & 63, slot = t >> 6;
    float sx = 0.f, sy = 0.f;
    for (int n = beg + slot; n < end; n += 4) {
        float2 v = *(const float2*)&h[(size_t)n * HID + c * 2];
        sx += signpow(v.x, false);
        sy += signpow(v.y, false);
    }
    smx[slot][c] = sx; smy[slot][c] = sy;
    __syncthreads();
    if (slot == 0) {
        sx = (smx[0][c] + smx[1][c]) + (smx[2][c] + smx[3][c]);
        sy = (smy[0][c] + smy[1][c]) + (smy[2][c] + smy[3][c]);
        float cnt = fmaxf((float)(end - beg), 1.0f);
        row[c * 2]     = fmaxf(signpow(sx / cnt, true), 0.f);
        row[c * 2 + 1] = fmaxf(signpow(sy / cnt, true), 0.f);
    }
    __syncthreads();
    if (t < 128) {
        float acc = bf0[t];
        #pragma unroll 8
        for (int k = 0; k < 128; k++) acc = fmaf(row[k], Wf0[k * 128 + t], acc);
        zrow[t] = fmaxf(acc, 0.f);
    }
    __syncthreads();
    if (t < OUT_DIM) {
        float a2 = bf1[t];
        #pragma unroll 8
        for (int k = 0; k < 128; k++) a2 = fmaf(zrow[k], Wf1[k * OUT_DIM + t], a2);
        out[g * OUT_DIM + t] = a2;
    }
}

// ---------------------------------------------------------------------------
static inline size_t align256(size_t x) { return (x + 255) & ~(size_t)255; }

extern "C" void kernel_launch(void* const* d_in, const int* in_sizes, int n_in,
                              void* d_out, int out_size, void* d_ws, size_t ws_size,
                              hipStream_t stream) {
    const float* x     = (const float*)d_in[0];
    const int*   ei    = (const int*)d_in[1];
    const int*   batch = (const int*)d_in[2];
    const float* W0  = (const float*)d_in[3];  const float* b0  = (const float*)d_in[4];
    const float* W1  = (const float*)d_in[5];  const float* b1  = (const float*)d_in[6];
    const float* W2  = (const float*)d_in[7];  const float* b2  = (const float*)d_in[8];
    const float* Wf0 = (const float*)d_in[9];  const float* bf0 = (const float*)d_in[10];
    const float* Wf1 = (const float*)d_in[11]; const float* bf1 = (const float*)d_in[12];
    float* out = (float*)d_out;

    char* p = (char*)d_ws;
    unsigned short* th = (unsigned short*)p; p += align256((size_t)M_PAD * HID * 2);
    short* bufAh = (short*)p; p += align256((size_t)M_PAD * HID * 2);
    short* bufAl = (short*)p; p += align256((size_t)M_PAD * HID * 2);
    short* bufBh = (short*)p; p += align256((size_t)M_PAD * HID * 2);
    short* bufBl = (short*)p; p += align256((size_t)M_PAD * HID * 2);
    float* h     = (float*)bufBh;   // aliases bufBh+bufBl (contiguous), live only after layer2
    unsigned* ebuf = (unsigned*)p; p += align256((size_t)NBUCK * BUCKCAP * 4);
    int*   gcnt    = (int*)p;   p += align256((size_t)NBUCK * 4);
    int*   offs    = (int*)p;   p += align256((size_t)(N_NODES + 1) * 4);
    int*   csr     = (int*)p;   p += align256((size_t)N_EDGES * 4);
    float* dis     = (float*)p; p += align256((size_t)N_NODES * 4);
    short* Wth     = (short*)p; p += align256((size_t)3 * HID * HID * 2);
    short* Wtl     = (short*)p; p += align256((size_t)3 * HID * HID * 2);

    hipMemsetAsync(gcnt, 0, (size_t)NBUCK * 4, stream);

    k_bucketize<<<ABLOCKS, 256, 0, stream>>>(ei, gcnt, ebuf);
    k_csr      <<<NBUCK, 256, 0, stream>>>(ebuf, gcnt, offs, dis, csr);

    dim3 wg(64, 3);
    k_wsplit3<<<wg, 256, 0, stream>>>(W0, W1, W2, Wth, Wtl);

    int agg_blocks = (N_NODES + 3) / 4;

    // layer 0: GEMM reads fp32 x directly (hi/lo split in staging)
    k_gemm_mfma<1><<<GEMM_GRID, 256, 0, stream>>>(x, nullptr, Wth, Wtl, th, dis);
    k_agg<<<agg_blocks, 256, 0, stream>>>(th, offs, csr, dis, b0,
                                          nullptr, bufBh, bufBl, 1);
    // layer 1
    k_gemm_mfma<0><<<GEMM_GRID, 256, 0, stream>>>(bufBh, bufBl,
                                                  Wth + HID * HID, Wtl + HID * HID, th, dis);
    k_agg<<<agg_blocks, 256, 0, stream>>>(th, offs, csr, dis, b1,
                                          nullptr, bufAh, bufAl, 1);
    // layer 2 (no relu, fp32 out for pooling)
    k_gemm_mfma<0><<<GEMM_GRID, 256, 0, stream>>>(bufAh, bufAl,
                                                  Wth + 2 * HID * HID, Wtl + 2 * HID * HID, th, dis);
    k_agg<<<agg_blocks, 256, 0, stream>>>(th, offs, csr, dis, b2,
                                          h, nullptr, nullptr, 0);

    k_poolff<<<NUM_GRAPHS, 256, 0, stream>>>(h, batch, Wf0, bf0, Wf1, bf1, out);
}

// Round 16
// 203.217 us; speedup vs baseline: 1.5880x; 1.0176x over previous
//
#include <hip/hip_runtime.h>

#define N_NODES   50000
#define M_PAD     50048            // 1564 * 32
#define N_TILES   1564
#define GEMM_GRID 782              // 2 tiles per block
#define N_EDGES   800000
#define HID       128
#define OUT_DIM   64
#define NUM_GRAPHS 512
#define EPS       1e-6f
#define NBUCK     196
#define BUCKCAP   6144
#define ABLOCKS   98

typedef __attribute__((ext_vector_type(8))) short short8;
typedef __attribute__((ext_vector_type(16))) float f32x16;

static __device__ __forceinline__ unsigned short f2bf(float f) {
    unsigned u = __builtin_bit_cast(unsigned, f);
    u += 0x7FFFu + ((u >> 16) & 1u);           // round-to-nearest-even
    return (unsigned short)(u >> 16);
}
static __device__ __forceinline__ float bf2f(unsigned short h) {
    unsigned u = ((unsigned)h) << 16;
    return __builtin_bit_cast(float, u);
}
static __device__ __forceinline__ float lo16(unsigned w) {
    return __builtin_bit_cast(float, w << 16);
}
static __device__ __forceinline__ float hi16(unsigned w) {
    return __builtin_bit_cast(float, w & 0xFFFF0000u);
}

static __device__ __forceinline__ float signpow(float x, bool sqrt_mode) {
    if (x == 0.0f) return 0.0f;
    float a = fabsf(x) + EPS;
    float v = sqrt_mode ? sqrtf(a) : a * a;
    return x > 0.0f ? v : -v;
}

// ---- W splits + gcnt zeroing (runs first) ----------------------------------
__global__ void k_wsplit3(const float* __restrict__ W0, const float* __restrict__ W1,
                          const float* __restrict__ W2, short* __restrict__ Wth,
                          short* __restrict__ Wtl, int* __restrict__ gcnt) {
    int which = blockIdx.y;
    if (which == 0 && blockIdx.x == 0 && threadIdx.x < NBUCK)
        gcnt[threadIdx.x] = 0;
    const float* W = which == 0 ? W0 : (which == 1 ? W1 : W2);
    int tid = blockIdx.x * blockDim.x + threadIdx.x;   // 16384
    int k = tid & 127, n = tid >> 7;
    float w = W[k * HID + n];
    unsigned short h = f2bf(w);
    Wth[which * HID * HID + n * HID + k] = (short)h;
    Wtl[which * HID * HID + n * HID + k] = (short)f2bf(w - bf2f(h));
}

// ---- CSR build, pass A: bucket edges by dst>>8 -----------------------------
__global__ __launch_bounds__(256) void k_bucketize(const int* __restrict__ ei,
                                                   int* __restrict__ gcnt,
                                                   unsigned* __restrict__ ebuf) {
    __shared__ int lcnt[NBUCK];
    __shared__ int lbase[NBUCK];
    int tid = threadIdx.x;
    for (int i = tid; i < NBUCK; i += 256) lcnt[i] = 0;
    __syncthreads();

    const uint4* src4 = (const uint4*)ei;
    const uint4* dst4 = (const uint4*)(ei + N_EDGES);
    int base4 = blockIdx.x * 2048;

    #pragma unroll 1
    for (int it = 0; it < 8; it++) {
        int i4 = base4 + it * 256 + tid;
        if (i4 < N_EDGES / 4) {
            uint4 d = dst4[i4];
            atomicAdd(&lcnt[d.x >> 8], 1);
            atomicAdd(&lcnt[d.y >> 8], 1);
            atomicAdd(&lcnt[d.z >> 8], 1);
            atomicAdd(&lcnt[d.w >> 8], 1);
        }
    }
    __syncthreads();
    for (int i = tid; i < NBUCK; i += 256) {
        lbase[i] = atomicAdd(&gcnt[i], lcnt[i]);
        lcnt[i] = 0;
    }
    __syncthreads();

    #pragma unroll 1
    for (int it = 0; it < 8; it++) {
        int i4 = base4 + it * 256 + tid;
        if (i4 < N_EDGES / 4) {
            uint4 d = dst4[i4];
            uint4 s = src4[i4];
            unsigned dd[4] = {d.x, d.y, d.z, d.w};
            unsigned ss[4] = {s.x, s.y, s.z, s.w};
            #pragma unroll
            for (int k = 0; k < 4; k++) {
                int b = dd[k] >> 8;
                int p = atomicAdd(&lcnt[b], 1);
                ebuf[(size_t)b * BUCKCAP + lbase[b] + p] = ss[k] | (dd[k] << 16);
            }
        }
    }
}

// ---- pass B: bucket prefix (internal) + per-node count/scan/fill ----------
__global__ __launch_bounds__(256) void k_csr(const unsigned* __restrict__ ebuf,
                                             const int* __restrict__ gcnt,
                                             int* __restrict__ offs,
                                             float* __restrict__ dis,
                                             int* __restrict__ csr) {
    __shared__ int cntA[256];
    __shared__ int scanA[256];
    __shared__ int sbase;
    int b = blockIdx.x;
    int t = threadIdx.x;
    int n0 = b * 256;

    int v = (t < NBUCK) ? gcnt[t] : 0;
    scanA[t] = v;
    __syncthreads();
    for (int off = 1; off < 256; off <<= 1) {
        int u = (t >= off) ? scanA[t - off] : 0;
        __syncthreads();
        scanA[t] += u;
        __syncthreads();
    }
    if (t == 0) sbase = (b == 0) ? 0 : scanA[b - 1];
    __syncthreads();
    int base  = sbase;
    int count = gcnt[b];
    const unsigned* eb = ebuf + (size_t)b * BUCKCAP;

    cntA[t] = 0;
    __syncthreads();
    for (int i = t; i < count; i += 256)
        atomicAdd(&cntA[eb[i] >> 16 & 0xFF], 1);
    __syncthreads();
    int c = cntA[t];
    scanA[t] = c;
    __syncthreads();
    for (int off = 1; off < 256; off <<= 1) {
        int u = (t >= off) ? scanA[t - off] : 0;
        __syncthreads();
        scanA[t] += u;
        __syncthreads();
    }
    int excl = scanA[t] - c;
    int n = n0 + t;
    if (n < N_NODES) {
        offs[n] = base + excl;
        dis[n]  = rsqrtf((float)c + 1.0f);
    }
    if (b == 0 && t == 0) offs[N_NODES] = N_EDGES;
    scanA[t] = excl;
    cntA[t] = 0;
    __syncthreads();
    for (int i = t; i < count; i += 256) {
        unsigned vv = eb[i];
        int ln = (vv >> 16) & 0xFF;
        int p = atomicAdd(&cntA[ln], 1);
        csr[base + scanA[ln] + p] = (int)(vv & 0xFFFFu);
    }
}

// ---- MFMA GEMM (32x32x16): W in regs, A staged via LDS; th (bf16) out ------
// FP32SRC=1: A fp32 [N_NODES x 128]; hi/lo split in staging; 24 MFMA/tile.
// FP32SRC=0: A bf16 [M_PAD x 128] (single array); 16 MFMA/tile (Ah*Wh+Ah*Wl).
template<int FP32SRC>
__global__ __launch_bounds__(256) void k_gemm_mfma(const void* __restrict__ Asrc,
                                                   const short* __restrict__ Wh,
                                                   const short* __restrict__ Wl,
                                                   unsigned short* __restrict__ th,
                                                   const float* __restrict__ scale) {
    __shared__ short As_h[32 * 128];   // 8 KB, col-group XOR-swizzled by row&7
    __shared__ short As_l[32 * 128];   // 8 KB (used only when FP32SRC)
    int tid  = threadIdx.x;
    int lane = tid & 63;
    int col  = (tid >> 6) * 32 + (lane & 31);
    int kh   = lane >> 5;
    int r    = lane & 31;

    short8 bh[8], bl[8];
    #pragma unroll
    for (int ks = 0; ks < 8; ks++) {
        bh[ks] = *(const short8*)(Wh + (size_t)col * HID + ks * 16 + kh * 8);
        bl[ks] = *(const short8*)(Wl + (size_t)col * HID + ks * 16 + kh * 8);
    }

    int su0 = tid, su1 = tid + 256;
    int sr0 = su0 >> 4, sc0 = su0 & 15;
    int sr1 = su1 >> 4, sc1 = su1 & 15;
    int sw0 = sr0 * 128 + ((sc0 ^ (sr0 & 7)) * 8);
    int sw1 = sr1 * 128 + ((sc1 ^ (sr1 & 7)) * 8);

    for (int tile = blockIdx.x; tile < N_TILES; tile += GEMM_GRID) {
        int row0 = tile * 32;
        __syncthreads();
        if (FP32SRC) {
            const float* gx = (const float*)Asrc;
            #pragma unroll
            for (int u = 0; u < 2; u++) {
                int sr = u ? sr1 : sr0, sc = u ? sc1 : sc0, sw = u ? sw1 : sw0;
                int gr = row0 + sr; if (gr >= N_NODES) gr = N_NODES - 1;
                const float* src = gx + (size_t)gr * HID + sc * 8;
                float4 a = ((const float4*)src)[0];
                float4 b = ((const float4*)src)[1];
                float vals[8] = {a.x, a.y, a.z, a.w, b.x, b.y, b.z, b.w};
                short8 hi, lo;
                #pragma unroll
                for (int j = 0; j < 8; j++) {
                    unsigned short hh = f2bf(vals[j]);
                    hi[j] = (short)hh;
                    lo[j] = (short)f2bf(vals[j] - bf2f(hh));
                }
                *(short8*)&As_h[sw] = hi;
                *(short8*)&As_l[sw] = lo;
            }
        } else {
            const short* gh = (const short*)Asrc + (size_t)row0 * HID;
            *(short8*)&As_h[sw0] = *(const short8*)(gh + sr0 * HID + sc0 * 8);
            *(short8*)&As_h[sw1] = *(const short8*)(gh + sr1 * HID + sc1 * 8);
        }
        __syncthreads();

        f32x16 acc = {0.f};
        if (FP32SRC) {
            short8 ah[8], al[8];
            #pragma unroll
            for (int ks = 0; ks < 8; ks++) {
                int cg = ks * 2 + kh;
                int off = r * 128 + ((cg ^ (r & 7)) * 8);
                ah[ks] = *(const short8*)&As_h[off];
                al[ks] = *(const short8*)&As_l[off];
            }
            #pragma unroll
            for (int ks = 0; ks < 8; ks++) {
                acc = __builtin_amdgcn_mfma_f32_32x32x16_bf16(ah[ks], bh[ks], acc, 0, 0, 0);
                acc = __builtin_amdgcn_mfma_f32_32x32x16_bf16(al[ks], bh[ks], acc, 0, 0, 0);
                acc = __builtin_amdgcn_mfma_f32_32x32x16_bf16(ah[ks], bl[ks], acc, 0, 0, 0);
            }
        } else {
            short8 ah[8];
            #pragma unroll
            for (int ks = 0; ks < 8; ks++) {
                int cg = ks * 2 + kh;
                int off = r * 128 + ((cg ^ (r & 7)) * 8);
                ah[ks] = *(const short8*)&As_h[off];
            }
            #pragma unroll
            for (int ks = 0; ks < 8; ks++) {
                acc = __builtin_amdgcn_mfma_f32_32x32x16_bf16(ah[ks], bh[ks], acc, 0, 0, 0);
                acc = __builtin_amdgcn_mfma_f32_32x32x16_bf16(ah[ks], bl[ks], acc, 0, 0, 0);
            }
        }

        #pragma unroll
        for (int reg = 0; reg < 16; reg++) {
            int row = row0 + (reg & 3) + 8 * (reg >> 2) + 4 * kh;
            float v = acc[reg] * scale[row];
            th[(size_t)row * HID + col] = f2bf(v);
        }
    }
}

// ---- GCN aggregation: row-major gather, uint4 (8 cols) per lane ------------
// mode 1: relu + bf16 hh out.  mode 0: fp32 hout, no relu.
__global__ __launch_bounds__(256) void k_agg(const unsigned short* __restrict__ th,
                                             const int* __restrict__ offs,
                                             const int* __restrict__ csr_src,
                                             const float* __restrict__ dis,
                                             const float* __restrict__ bias,
                                             float* __restrict__ hout,
                                             short* __restrict__ hh,
                                             int mode) {
    int node = blockIdx.x * 4 + (threadIdx.x >> 6);
    if (node >= N_NODES) return;
    int lane = threadIdx.x & 63;
    int c  = lane & 15;          // col group: cols [c*8, c*8+8)
    int e  = lane >> 4;          // edge slot 0..3
    int beg = offs[node], end = offs[node + 1];
    float dn = dis[node];

    float a[8] = {};
    for (int j = beg; j < end; j += 8) {
        #pragma unroll
        for (int k = 0; k < 2; k++) {
            int jj = j + k * 4 + e;
            int jc = jj < end ? jj : end - 1;
            int s = csr_src[jc];
            float m = (jj < end) ? 1.0f : 0.0f;
            uint4 v = *(const uint4*)&th[(size_t)s * HID + c * 8];
            a[0] = fmaf(lo16(v.x), m, a[0]);
            a[1] = fmaf(hi16(v.x), m, a[1]);
            a[2] = fmaf(lo16(v.y), m, a[2]);
            a[3] = fmaf(hi16(v.y), m, a[3]);
            a[4] = fmaf(lo16(v.z), m, a[4]);
            a[5] = fmaf(hi16(v.z), m, a[5]);
            a[6] = fmaf(lo16(v.w), m, a[6]);
            a[7] = fmaf(hi16(v.w), m, a[7]);
        }
    }
    #pragma unroll
    for (int i = 0; i < 8; i++) {
        a[i] += __shfl_xor(a[i], 16);
        a[i] += __shfl_xor(a[i], 32);
    }

    if (e == 0) {
        uint4 sh = *(const uint4*)&th[(size_t)node * HID + c * 8];
        float4 b0 = *(const float4*)&bias[c * 8];
        float4 b1 = *(const float4*)&bias[c * 8 + 4];
        float o[8];
        o[0] = (a[0] + lo16(sh.x)) * dn + b0.x;
        o[1] = (a[1] + hi16(sh.x)) * dn + b0.y;
        o[2] = (a[2] + lo16(sh.y)) * dn + b0.z;
        o[3] = (a[3] + hi16(sh.y)) * dn + b0.w;
        o[4] = (a[4] + lo16(sh.z)) * dn + b1.x;
        o[5] = (a[5] + hi16(sh.z)) * dn + b1.y;
        o[6] = (a[6] + lo16(sh.w)) * dn + b1.z;
        o[7] = (a[7] + hi16(sh.w)) * dn + b1.w;
        if (mode == 1) {
            ushort4 vh0, vh1;
            #pragma unroll
            for (int i = 0; i < 8; i++) o[i] = fmaxf(o[i], 0.f);
            vh0.x = f2bf(o[0]); vh0.y = f2bf(o[1]); vh0.z = f2bf(o[2]); vh0.w = f2bf(o[3]);
            vh1.x = f2bf(o[4]); vh1.y = f2bf(o[5]); vh1.z = f2bf(o[6]); vh1.w = f2bf(o[7]);
            *(ushort4*)&hh[(size_t)node * HID + c * 8]     = vh0;
            *(ushort4*)&hh[(size_t)node * HID + c * 8 + 4] = vh1;
        } else {
            float4 o0 = make_float4(o[0], o[1], o[2], o[3]);
            float4 o1 = make_float4(o[4], o[5], o[6], o[7]);
            *(float4*)&hout[(size_t)node * HID + c * 8]     = o0;
            *(float4*)&hout[(size_t)node * HID + c * 8 + 4] = o1;
        }
    }
}

// ---- pool (gen-mean p=2) + FF head, one block per graph --------------------
__global__ __launch_bounds__(256) void k_poolff(const float* __restrict__ h,
                                                const int* __restrict__ batch,
                                                const float* __restrict__ Wf0,
                                                const float* __restrict__ bf0,
                                                const float* __restrict__ Wf1,
                                                const float* __restrict__ bf1,
                                                float* __restrict__ out) {
    __shared__ float smx[4][64], smy[4][64];
    __shared__ float row[128], zrow[128];
    __shared__ int bnd[2];
    int g = blockIdx.x;
    int t = threadIdx.x;
    if (t < 2) {
        int target = g + t;
        int lo = 0, hi = N_NODES;
        while (lo < hi) {
            int mid = (lo + hi) >> 1;
            if (batch[mid] < target) lo = mid + 1; else hi = mid;
        }
        bnd[t] = lo;
    }
    __syncthreads();
    int beg = bnd[0], end = bnd[1];

    int c = t & 63, slot = t >> 6;
    float sx = 0.f, sy = 0.f;
    for (int n = beg + slot; n < end; n += 4) {
        float2 v = *(const float2*)&h[(size_t)n * HID + c * 2];
        sx += signpow(v.x, false);
        sy += signpow(v.y, false);
    }
    smx[slot][c] = sx; smy[slot][c] = sy;
    __syncthreads();
    if (slot == 0) {
        sx = (smx[0][c] + smx[1][c]) + (smx[2][c] + smx[3][c]);
        sy = (smy[0][c] + smy[1][c]) + (smy[2][c] + smy[3][c]);
        float cnt = fmaxf((float)(end - beg), 1.0f);
        row[c * 2]     = fmaxf(signpow(sx / cnt, true), 0.f);
        row[c * 2 + 1] = fmaxf(signpow(sy / cnt, true), 0.f);
    }
    __syncthreads();
    if (t < 128) {
        float acc = bf0[t];
        #pragma unroll 8
        for (int k = 0; k < 128; k++) acc = fmaf(row[k], Wf0[k * 128 + t], acc);
        zrow[t] = fmaxf(acc, 0.f);
    }
    __syncthreads();
    if (t < OUT_DIM) {
        float a2 = bf1[t];
        #pragma unroll 8
        for (int k = 0; k < 128; k++) a2 = fmaf(zrow[k], Wf1[k * OUT_DIM + t], a2);
        out[g * OUT_DIM + t] = a2;
    }
}

// ---------------------------------------------------------------------------
static inline size_t align256(size_t x) { return (x + 255) & ~(size_t)255; }

extern "C" void kernel_launch(void* const* d_in, const int* in_sizes, int n_in,
                              void* d_out, int out_size, void* d_ws, size_t ws_size,
                              hipStream_t stream) {
    const float* x     = (const float*)d_in[0];
    const int*   ei    = (const int*)d_in[1];
    const int*   batch = (const int*)d_in[2];
    const float* W0  = (const float*)d_in[3];  const float* b0  = (const float*)d_in[4];
    const float* W1  = (const float*)d_in[5];  const float* b1  = (const float*)d_in[6];
    const float* W2  = (const float*)d_in[7];  const float* b2  = (const float*)d_in[8];
    const float* Wf0 = (const float*)d_in[9];  const float* bf0 = (const float*)d_in[10];
    const float* Wf1 = (const float*)d_in[11]; const float* bf1 = (const float*)d_in[12];
    float* out = (float*)d_out;

    char* p = (char*)d_ws;
    unsigned short* th = (unsigned short*)p; p += align256((size_t)M_PAD * HID * 2);
    short* hA    = (short*)p; p += align256((size_t)M_PAD * HID * 2);
    short* hB    = (short*)p; p += align256((size_t)M_PAD * HID * 2);
    float* h     = (float*)p; p += align256((size_t)M_PAD * HID * 4);
    unsigned* ebuf = (unsigned*)p; p += align256((size_t)NBUCK * BUCKCAP * 4);
    int*   gcnt    = (int*)p;   p += align256((size_t)NBUCK * 4);
    int*   offs    = (int*)p;   p += align256((size_t)(N_NODES + 1) * 4);
    int*   csr     = (int*)p;   p += align256((size_t)N_EDGES * 4);
    float* dis     = (float*)p; p += align256((size_t)N_NODES * 4);
    short* Wth     = (short*)p; p += align256((size_t)3 * HID * HID * 2);
    short* Wtl     = (short*)p; p += align256((size_t)3 * HID * HID * 2);

    dim3 wg(64, 3);
    k_wsplit3<<<wg, 256, 0, stream>>>(W0, W1, W2, Wth, Wtl, gcnt);
    k_bucketize<<<ABLOCKS, 256, 0, stream>>>(ei, gcnt, ebuf);
    k_csr      <<<NBUCK, 256, 0, stream>>>(ebuf, gcnt, offs, dis, csr);

    int agg_blocks = (N_NODES + 3) / 4;

    // layer 0: GEMM reads fp32 x directly (hi/lo split in staging, 24 MFMA)
    k_gemm_mfma<1><<<GEMM_GRID, 256, 0, stream>>>(x, Wth, Wtl, th, dis);
    k_agg<<<agg_blocks, 256, 0, stream>>>(th, offs, csr, dis, b0, nullptr, hB, 1);
    // layer 1 (bf16 A, 16 MFMA)
    k_gemm_mfma<0><<<GEMM_GRID, 256, 0, stream>>>(hB, Wth + HID * HID, Wtl + HID * HID, th, dis);
    k_agg<<<agg_blocks, 256, 0, stream>>>(th, offs, csr, dis, b1, nullptr, hA, 1);
    // layer 2 (no relu, fp32 out for pooling)
    k_gemm_mfma<0><<<GEMM_GRID, 256, 0, stream>>>(hA, Wth + 2 * HID * HID, Wtl + 2 * HID * HID, th, dis);
    k_agg<<<agg_blocks, 256, 0, stream>>>(th, offs, csr, dis, b2, h, nullptr, 0);

    k_poolff<<<NUM_GRAPHS, 256, 0, stream>>>(h, batch, Wf0, bf0, Wf1, bf1, out);
}